// Round 1
// baseline (352.582 us; speedup 1.0000x reference)
//
#include <hip/hip_runtime.h>
#include <math.h>

#define B_ 8
#define T_ 2048
#define C_ 1024
#define H_ 64

// ---------------------------------------------------------------------------
// Kernel 1: fused projections q = x@Wq, k = x@Wk, v = x@Wv
// M = B*T = 16384 rows, K = 1024, N = 192 (64 per matrix), fp32 vector FMA.
// Block: 256 threads handles 64 rows x 192 cols. KC=32 K-chunks staged in LDS.
// Thread (ty,tx): rows ty*4..+3, cols tx*12..+11 (contiguous -> float4 LDS reads)
// ---------------------------------------------------------------------------
__global__ __launch_bounds__(256) void proj_kernel(
    const float* __restrict__ x,
    const float* __restrict__ Wq,
    const float* __restrict__ Wk,
    const float* __restrict__ Wv,
    float* __restrict__ qo,
    float* __restrict__ ko,
    float* __restrict__ vo)
{
    __shared__ float xs[64][33];    // pad 33: conflict-free scalar access
    __shared__ float ws[32][192];   // [kk][col], col 0..63=q, 64..127=k, 128..191=v

    const int tid = threadIdx.x;
    const int m0  = blockIdx.x * 64;
    const int ty  = tid >> 4;   // 0..15 -> rows ty*4..ty*4+3
    const int tx  = tid & 15;   // 0..15 -> cols tx*12..tx*12+11

    float acc[4][12];
#pragma unroll
    for (int i = 0; i < 4; ++i)
#pragma unroll
        for (int c = 0; c < 12; ++c) acc[i][c] = 0.f;

    for (int kbase = 0; kbase < C_; kbase += 32) {
        __syncthreads();
        // stage x tile: 64 rows x 32 cols (512 float4 loads)
#pragma unroll
        for (int t = 0; t < 2; ++t) {
            int idx = tid + t * 256;          // 0..511 (float4 index)
            int rr  = idx >> 3;               // 0..63
            int c4  = idx & 7;                // 0..7
            float4 xv = *reinterpret_cast<const float4*>(
                &x[(size_t)(m0 + rr) * C_ + kbase + c4 * 4]);
            xs[rr][c4 * 4 + 0] = xv.x;
            xs[rr][c4 * 4 + 1] = xv.y;
            xs[rr][c4 * 4 + 2] = xv.z;
            xs[rr][c4 * 4 + 3] = xv.w;
        }
        // stage W tile: 32 kk x 192 cols (1536 float4 loads)
#pragma unroll
        for (int t = 0; t < 6; ++t) {
            int idx = tid + t * 256;          // 0..1535 (float4 index)
            int kk  = idx / 48;               // 0..31
            int c4  = idx - kk * 48;          // 0..47
            int col0 = c4 * 4;
            const float* Wsel;
            int colh;
            if (col0 < 64)       { Wsel = Wq; colh = col0; }
            else if (col0 < 128) { Wsel = Wk; colh = col0 - 64; }
            else                 { Wsel = Wv; colh = col0 - 128; }
            float4 wv = *reinterpret_cast<const float4*>(
                &Wsel[(size_t)(kbase + kk) * H_ + colh]);
            *reinterpret_cast<float4*>(&ws[kk][col0]) = wv;
        }
        __syncthreads();

#pragma unroll 4
        for (int kk = 0; kk < 32; ++kk) {
            float xv[4];
#pragma unroll
            for (int i = 0; i < 4; ++i) xv[i] = xs[ty * 4 + i][kk];
            float wv[12];
            const float4* wrow = reinterpret_cast<const float4*>(&ws[kk][tx * 12]);
            *reinterpret_cast<float4*>(&wv[0]) = wrow[0];
            *reinterpret_cast<float4*>(&wv[4]) = wrow[1];
            *reinterpret_cast<float4*>(&wv[8]) = wrow[2];
#pragma unroll
            for (int i = 0; i < 4; ++i)
#pragma unroll
                for (int c = 0; c < 12; ++c)
                    acc[i][c] = fmaf(xv[i], wv[c], acc[i][c]);
        }
    }

    // write out: col<64 -> q, <128 -> k, else v
#pragma unroll
    for (int i = 0; i < 4; ++i) {
        const size_t m = (size_t)(m0 + ty * 4 + i);
#pragma unroll
        for (int c = 0; c < 12; ++c) {
            int col = tx * 12 + c;
            float val = acc[i][c];
            if (col < 64)        qo[m * H_ + col]       = val;
            else if (col < 128)  ko[m * H_ + col - 64]  = val;
            else                 vo[m * H_ + col - 128] = val;
        }
    }
}

// ---------------------------------------------------------------------------
// Kernel 2: causal flash attention, fp32.
// Grid (T/64, B). Block 256 threads handles 64 query rows.
// Thread (r = tid>>2, cq = tid&3): query row r, col/h quarter cq (16 elems).
// K stored transposed in LDS (KT[h][s]) so the S loop does float4 row reads.
// ---------------------------------------------------------------------------
__global__ __launch_bounds__(256) void attn_kernel(
    const float* __restrict__ q,
    const float* __restrict__ k,
    const float* __restrict__ v,
    float* __restrict__ out)
{
    __shared__ float Qs[64][65];   // [row][h], pad 65
    __shared__ float KT[64][68];   // [h][s],  pad 68 (16B-aligned rows)
    __shared__ float Vs[64][64];   // [s][h]
    __shared__ float Ps[64][68];   // [row][s], pad 68

    const int tid = threadIdx.x;
    const int b   = blockIdx.y;
    const int qb  = blockIdx.x;
    const int r   = tid >> 2;   // 0..63 query row in tile
    const int cq  = tid & 3;    // quarter

    const size_t baseq = ((size_t)b * T_ + (size_t)qb * 64) * H_;

    // load Q tile
#pragma unroll
    for (int t = 0; t < 4; ++t) {
        int idx = tid + t * 256;        // float4 index 0..1023
        int row = idx >> 4, h4 = idx & 15;
        float4 qv = *reinterpret_cast<const float4*>(&q[baseq + (size_t)row * H_ + h4 * 4]);
        Qs[row][h4 * 4 + 0] = qv.x;
        Qs[row][h4 * 4 + 1] = qv.y;
        Qs[row][h4 * 4 + 2] = qv.z;
        Qs[row][h4 * 4 + 3] = qv.w;
    }

    float m_i = -INFINITY;
    float l_i = 0.f;
    float oacc[16];
#pragma unroll
    for (int i = 0; i < 16; ++i) oacc[i] = 0.f;

    for (int kb = 0; kb <= qb; ++kb) {
        __syncthreads();   // protect LDS before restaging
        const size_t basek = ((size_t)b * T_ + (size_t)kb * 64) * H_;
#pragma unroll
        for (int t = 0; t < 4; ++t) {
            int idx = tid + t * 256;
            int row = idx >> 4, h4 = idx & 15;
            float4 kv = *reinterpret_cast<const float4*>(&k[basek + (size_t)row * H_ + h4 * 4]);
            KT[h4 * 4 + 0][row] = kv.x;
            KT[h4 * 4 + 1][row] = kv.y;
            KT[h4 * 4 + 2][row] = kv.z;
            KT[h4 * 4 + 3][row] = kv.w;
            float4 vv = *reinterpret_cast<const float4*>(&v[basek + (size_t)row * H_ + h4 * 4]);
            *reinterpret_cast<float4*>(&Vs[row][h4 * 4]) = vv;
        }
        __syncthreads();

        // ---- S = Q K^T (thread: row r, key cols cq*16..+15) ----
        float s[16];
#pragma unroll
        for (int c = 0; c < 16; ++c) s[c] = 0.f;

#pragma unroll 8
        for (int kk = 0; kk < 64; ++kk) {
            float qv = Qs[r][kk];
            float kv[16];
            const float4* kt = reinterpret_cast<const float4*>(&KT[kk][cq * 16]);
            *reinterpret_cast<float4*>(&kv[0])  = kt[0];
            *reinterpret_cast<float4*>(&kv[4])  = kt[1];
            *reinterpret_cast<float4*>(&kv[8])  = kt[2];
            *reinterpret_cast<float4*>(&kv[12]) = kt[3];
#pragma unroll
            for (int c = 0; c < 16; ++c) s[c] = fmaf(qv, kv[c], s[c]);
        }

        // scale + causal mask
#pragma unroll
        for (int c = 0; c < 16; ++c) s[c] *= 0.03125f;   // 1024^-0.5
        if (kb == qb) {
#pragma unroll
            for (int c = 0; c < 16; ++c)
                if (cq * 16 + c > r) s[c] = -INFINITY;
        }

        // row max across 16 local + 4 lanes sharing the row
        float mx = s[0];
#pragma unroll
        for (int c = 1; c < 16; ++c) mx = fmaxf(mx, s[c]);
        mx = fmaxf(mx, __shfl_xor(mx, 1));
        mx = fmaxf(mx, __shfl_xor(mx, 2));

        float m_new = fmaxf(m_i, mx);
        float alpha = __expf(m_i - m_new);

        float p[16];
        float lsum = 0.f;
#pragma unroll
        for (int c = 0; c < 16; ++c) {
            p[c] = __expf(s[c] - m_new);
            lsum += p[c];
        }
        lsum += __shfl_xor(lsum, 1);
        lsum += __shfl_xor(lsum, 2);

        l_i = l_i * alpha + lsum;
        m_i = m_new;
#pragma unroll
        for (int i = 0; i < 16; ++i) oacc[i] *= alpha;

        // stage P
        *reinterpret_cast<float4*>(&Ps[r][cq * 16 + 0])  = *reinterpret_cast<float4*>(&p[0]);
        *reinterpret_cast<float4*>(&Ps[r][cq * 16 + 4])  = *reinterpret_cast<float4*>(&p[4]);
        *reinterpret_cast<float4*>(&Ps[r][cq * 16 + 8])  = *reinterpret_cast<float4*>(&p[8]);
        *reinterpret_cast<float4*>(&Ps[r][cq * 16 + 12]) = *reinterpret_cast<float4*>(&p[12]);
        __syncthreads();

        // ---- O += P V (thread: row r, h cols cq*16..+15) ----
#pragma unroll 8
        for (int s0 = 0; s0 < 64; ++s0) {
            float pv = Ps[r][s0];
            float vv[16];
            const float4* vr = reinterpret_cast<const float4*>(&Vs[s0][cq * 16]);
            *reinterpret_cast<float4*>(&vv[0])  = vr[0];
            *reinterpret_cast<float4*>(&vv[4])  = vr[1];
            *reinterpret_cast<float4*>(&vv[8])  = vr[2];
            *reinterpret_cast<float4*>(&vv[12]) = vr[3];
#pragma unroll
            for (int i = 0; i < 16; ++i) oacc[i] = fmaf(pv, vv[i], oacc[i]);
        }
    }

    const float inv = 1.f / l_i;
    float ov[16];
#pragma unroll
    for (int i = 0; i < 16; ++i) ov[i] = oacc[i] * inv;

    float4* od = reinterpret_cast<float4*>(&out[baseq + (size_t)r * H_ + cq * 16]);
    od[0] = *reinterpret_cast<float4*>(&ov[0]);
    od[1] = *reinterpret_cast<float4*>(&ov[4]);
    od[2] = *reinterpret_cast<float4*>(&ov[8]);
    od[3] = *reinterpret_cast<float4*>(&ov[12]);
}

// ---------------------------------------------------------------------------
extern "C" void kernel_launch(void* const* d_in, const int* in_sizes, int n_in,
                              void* d_out, int out_size, void* d_ws, size_t ws_size,
                              hipStream_t stream)
{
    // setup_inputs order: x, Wk, Wq, Wv
    const float* x  = (const float*)d_in[0];
    const float* Wk = (const float*)d_in[1];
    const float* Wq = (const float*)d_in[2];
    const float* Wv = (const float*)d_in[3];
    float* out = (float*)d_out;

    const size_t nqkv = (size_t)B_ * T_ * H_;   // 1M elements each
    float* qbuf = (float*)d_ws;
    float* kbuf = qbuf + nqkv;
    float* vbuf = kbuf + nqkv;

    proj_kernel<<<dim3((B_ * T_) / 64), 256, 0, stream>>>(x, Wq, Wk, Wv, qbuf, kbuf, vbuf);
    attn_kernel<<<dim3(T_ / 64, B_), 256, 0, stream>>>(qbuf, kbuf, vbuf, out);
}

// Round 2
// 132.210 us; speedup vs baseline: 2.6668x; 2.6668x over previous
//
#include <hip/hip_runtime.h>
#include <math.h>

#define B_ 8
#define T_ 2048
#define C_ 1024
#define H_ 64

typedef __attribute__((ext_vector_type(8))) short bf16x8;
typedef __attribute__((ext_vector_type(4))) float f32x4;

static __device__ __forceinline__ short f2bf(float f) {
    unsigned u = __float_as_uint(f);
    unsigned r = (u + 0x7FFFu + ((u >> 16) & 1u)) >> 16;   // RNE
    return (short)r;
}

// ---------------------------------------------------------------------------
// Kernel 0: WT[n][k] = W[k][n] as bf16. n: 0-63 = Wq cols, 64-127 = Wk, 128-191 = Wv.
// ---------------------------------------------------------------------------
__global__ __launch_bounds__(256) void wtrans_kernel(
    const float* __restrict__ Wq, const float* __restrict__ Wk,
    const float* __restrict__ Wv, short* __restrict__ WT)
{
    const int n  = blockIdx.x;          // 0..191
    const int k0 = threadIdx.x * 4;     // 0..1020
    const float* Wsel = (n < 64) ? Wq : (n < 128 ? Wk : Wv);
    const int h = n & 63;
    short4 pk;
    pk.x = f2bf(Wsel[(size_t)(k0 + 0) * H_ + h]);
    pk.y = f2bf(Wsel[(size_t)(k0 + 1) * H_ + h]);
    pk.z = f2bf(Wsel[(size_t)(k0 + 2) * H_ + h]);
    pk.w = f2bf(Wsel[(size_t)(k0 + 3) * H_ + h]);
    *reinterpret_cast<short4*>(&WT[(size_t)n * C_ + k0]) = pk;
}

// ---------------------------------------------------------------------------
// Kernel 1: MFMA projections. C = X(bf16) * W(bf16), M=16384, K=1024, N=192.
// Block: 256 thr = 4 waves, 64 rows x 192 cols. Wave wq: 16 rows.
// mfma_f32_16x16x32_bf16. A-frag: lane row=l&15, k=(l>>4)*8 contiguous.
// B-frag: lane col=l&15, k contiguous (so Ws rows are output-col-major = W^T).
// C-frag: col=l&15, row=(l>>4)*4+reg.
// Outputs: q,k row-major bf16 [B*T][64]; v transposed bf16 [B][64][T].
// ---------------------------------------------------------------------------
__global__ __launch_bounds__(256, 2) void proj_kernel(
    const float* __restrict__ x, const short* __restrict__ WT,
    short* __restrict__ qg, short* __restrict__ kg, short* __restrict__ vT)
{
    __shared__ short Xs[64][72];    // pad 72: 144B rows -> 2-way conflicts (free)
    __shared__ short Ws[192][72];

    const int tid  = threadIdx.x;
    const int m0   = blockIdx.x * 64;
    const int wq   = tid >> 6;
    const int lane = tid & 63;
    const int col  = lane & 15;
    const int g    = lane >> 4;

    f32x4 acc[12];
#pragma unroll
    for (int nt = 0; nt < 12; ++nt) acc[nt] = (f32x4){0.f, 0.f, 0.f, 0.f};

    for (int kb = 0; kb < C_; kb += 64) {
        __syncthreads();
        // stage X tile (f32 -> bf16): thread: row tid>>2, 16 k at (tid&3)*16
        {
            const int r  = tid >> 2;
            const int kq = (tid & 3) * 16;
            const float4* src = reinterpret_cast<const float4*>(
                &x[(size_t)(m0 + r) * C_ + kb + kq]);
            float4 a0 = src[0], a1 = src[1], a2 = src[2], a3 = src[3];
            bf16x8 v0, v1;
            v0[0] = f2bf(a0.x); v0[1] = f2bf(a0.y); v0[2] = f2bf(a0.z); v0[3] = f2bf(a0.w);
            v0[4] = f2bf(a1.x); v0[5] = f2bf(a1.y); v0[6] = f2bf(a1.z); v0[7] = f2bf(a1.w);
            v1[0] = f2bf(a2.x); v1[1] = f2bf(a2.y); v1[2] = f2bf(a2.z); v1[3] = f2bf(a2.w);
            v1[4] = f2bf(a3.x); v1[5] = f2bf(a3.y); v1[6] = f2bf(a3.z); v1[7] = f2bf(a3.w);
            *reinterpret_cast<bf16x8*>(&Xs[r][kq])     = v0;
            *reinterpret_cast<bf16x8*>(&Xs[r][kq + 8]) = v1;
        }
        // stage W^T tile: 192 rows x 64 k bf16, 1536 16B chunks
#pragma unroll
        for (int t = 0; t < 6; ++t) {
            int idx = tid + t * 256;
            int row = idx >> 3;
            int c8  = (idx & 7) * 8;
            bf16x8 wv = *reinterpret_cast<const bf16x8*>(&WT[(size_t)row * C_ + kb + c8]);
            *reinterpret_cast<bf16x8*>(&Ws[row][c8]) = wv;
        }
        __syncthreads();

        bf16x8 a0 = *reinterpret_cast<const bf16x8*>(&Xs[wq * 16 + col][g * 8]);
        bf16x8 a1 = *reinterpret_cast<const bf16x8*>(&Xs[wq * 16 + col][32 + g * 8]);
#pragma unroll
        for (int nt = 0; nt < 12; ++nt) {
            bf16x8 b0 = *reinterpret_cast<const bf16x8*>(&Ws[nt * 16 + col][g * 8]);
            bf16x8 b1 = *reinterpret_cast<const bf16x8*>(&Ws[nt * 16 + col][32 + g * 8]);
            acc[nt] = __builtin_amdgcn_mfma_f32_16x16x32_bf16(a0, b0, acc[nt], 0, 0, 0);
            acc[nt] = __builtin_amdgcn_mfma_f32_16x16x32_bf16(a1, b1, acc[nt], 0, 0, 0);
        }
    }

    // epilogue
    const int trow0 = m0 + wq * 16 + g * 4;
#pragma unroll
    for (int nt = 0; nt < 4; ++nt)
#pragma unroll
        for (int r = 0; r < 4; ++r)
            qg[(size_t)(trow0 + r) * H_ + nt * 16 + col] = f2bf(acc[nt][r]);
#pragma unroll
    for (int nt = 4; nt < 8; ++nt)
#pragma unroll
        for (int r = 0; r < 4; ++r)
            kg[(size_t)(trow0 + r) * H_ + (nt - 4) * 16 + col] = f2bf(acc[nt][r]);
    {
        const int bb   = trow0 >> 11;
        const int tloc = trow0 & 2047;
#pragma unroll
        for (int nt = 8; nt < 12; ++nt) {
            short4 pk;
            pk.x = f2bf(acc[nt][0]); pk.y = f2bf(acc[nt][1]);
            pk.z = f2bf(acc[nt][2]); pk.w = f2bf(acc[nt][3]);
            const int h = (nt - 8) * 16 + col;
            *reinterpret_cast<short4*>(&vT[((size_t)bb * H_ + h) * T_ + tloc]) = pk;
        }
    }
}

// ---------------------------------------------------------------------------
// Kernel 2: barrier-free MFMA flash attention.
// Grid (32, 8), 256 thr = 4 independent waves; wave owns 16 query rows.
// Q frags in registers; K/V^T frags direct from global (L2-resident, 16B/lane);
// P re-laid-out via wave-private padded LDS. No __syncthreads in the kb loop.
// qb reversed so longest blocks dispatch first.
// ---------------------------------------------------------------------------
__global__ __launch_bounds__(256) void attn_kernel(
    const short* __restrict__ qg, const short* __restrict__ kg,
    const short* __restrict__ vT, float* __restrict__ out)
{
    __shared__ short Ps[4][16][72];   // wave-private P tile, padded

    const int tid  = threadIdx.x;
    const int wq   = tid >> 6;
    const int lane = tid & 63;
    const int col  = lane & 15;
    const int g    = lane >> 4;
    const int b    = blockIdx.y;
    const int qb   = (int)(gridDim.x - 1) - (int)blockIdx.x;   // reverse order
    const int qt0  = qb * 64 + wq * 16;

    const size_t qkbase = (size_t)b * T_ * H_;

    const bf16x8 qf0 = *reinterpret_cast<const bf16x8*>(
        &qg[qkbase + (size_t)(qt0 + col) * H_ + g * 8]);
    const bf16x8 qf1 = *reinterpret_cast<const bf16x8*>(
        &qg[qkbase + (size_t)(qt0 + col) * H_ + 32 + g * 8]);

    float m_i[4], l_i[4];
    f32x4 acc_o[4];
#pragma unroll
    for (int r = 0; r < 4; ++r) { m_i[r] = -INFINITY; l_i[r] = 0.f; }
#pragma unroll
    for (int nt = 0; nt < 4; ++nt) acc_o[nt] = (f32x4){0.f, 0.f, 0.f, 0.f};

    for (int kb = 0; kb <= qb; ++kb) {
        // ---- K fragments (direct global, L2-hit) ----
        const short* kbp = &kg[qkbase + (size_t)kb * 64 * H_];
        bf16x8 kf0[4], kf1[4];
#pragma unroll
        for (int nt = 0; nt < 4; ++nt) {
            kf0[nt] = *reinterpret_cast<const bf16x8*>(&kbp[(nt * 16 + col) * H_ + g * 8]);
            kf1[nt] = *reinterpret_cast<const bf16x8*>(&kbp[(nt * 16 + col) * H_ + 32 + g * 8]);
        }
        f32x4 s[4];
#pragma unroll
        for (int nt = 0; nt < 4; ++nt) {
            s[nt] = (f32x4){0.f, 0.f, 0.f, 0.f};
            s[nt] = __builtin_amdgcn_mfma_f32_16x16x32_bf16(qf0, kf0[nt], s[nt], 0, 0, 0);
            s[nt] = __builtin_amdgcn_mfma_f32_16x16x32_bf16(qf1, kf1[nt], s[nt], 0, 0, 0);
        }

        // ---- V^T fragments issued early (latency hidden under softmax) ----
        const short* vbp = &vT[(size_t)b * H_ * T_ + kb * 64];
        bf16x8 vf0[4], vf1[4];
#pragma unroll
        for (int nt = 0; nt < 4; ++nt) {
            vf0[nt] = *reinterpret_cast<const bf16x8*>(&vbp[(size_t)(nt * 16 + col) * T_ + g * 8]);
            vf1[nt] = *reinterpret_cast<const bf16x8*>(&vbp[(size_t)(nt * 16 + col) * T_ + 32 + g * 8]);
        }

        // ---- scale + causal mask ----
#pragma unroll
        for (int nt = 0; nt < 4; ++nt)
#pragma unroll
            for (int r = 0; r < 4; ++r) s[nt][r] *= 0.03125f;   // 1024^-0.5
        if (kb == qb) {
#pragma unroll
            for (int nt = 0; nt < 4; ++nt)
#pragma unroll
                for (int r = 0; r < 4; ++r)
                    if (nt * 16 + col > wq * 16 + g * 4 + r) s[nt][r] = -INFINITY;
        }

        // ---- online softmax (rows g*4+r live in lanes g*16..g*16+15) ----
        float mx[4];
#pragma unroll
        for (int r = 0; r < 4; ++r) {
            mx[r] = fmaxf(fmaxf(s[0][r], s[1][r]), fmaxf(s[2][r], s[3][r]));
            mx[r] = fmaxf(mx[r], __shfl_xor(mx[r], 1));
            mx[r] = fmaxf(mx[r], __shfl_xor(mx[r], 2));
            mx[r] = fmaxf(mx[r], __shfl_xor(mx[r], 4));
            mx[r] = fmaxf(mx[r], __shfl_xor(mx[r], 8));
        }
        float alpha[4];
#pragma unroll
        for (int r = 0; r < 4; ++r) {
            float mn = fmaxf(m_i[r], mx[r]);
            alpha[r] = __expf(m_i[r] - mn);
            m_i[r]   = mn;
        }
        float p[4][4];
#pragma unroll
        for (int nt = 0; nt < 4; ++nt)
#pragma unroll
            for (int r = 0; r < 4; ++r) p[nt][r] = __expf(s[nt][r] - m_i[r]);
        float lsum[4];
#pragma unroll
        for (int r = 0; r < 4; ++r) {
            lsum[r] = (p[0][r] + p[1][r]) + (p[2][r] + p[3][r]);
            lsum[r] += __shfl_xor(lsum[r], 1);
            lsum[r] += __shfl_xor(lsum[r], 2);
            lsum[r] += __shfl_xor(lsum[r], 4);
            lsum[r] += __shfl_xor(lsum[r], 8);
            l_i[r] = l_i[r] * alpha[r] + lsum[r];
        }
#pragma unroll
        for (int nt = 0; nt < 4; ++nt)
#pragma unroll
            for (int r = 0; r < 4; ++r) acc_o[nt][r] *= alpha[r];

        // ---- P -> LDS (bf16), re-read as A fragments ----
#pragma unroll
        for (int nt = 0; nt < 4; ++nt)
#pragma unroll
            for (int r = 0; r < 4; ++r)
                Ps[wq][g * 4 + r][nt * 16 + col] = f2bf(p[nt][r]);

        bf16x8 ap0 = *reinterpret_cast<const bf16x8*>(&Ps[wq][col][g * 8]);
        bf16x8 ap1 = *reinterpret_cast<const bf16x8*>(&Ps[wq][col][32 + g * 8]);

#pragma unroll
        for (int nt = 0; nt < 4; ++nt) {
            acc_o[nt] = __builtin_amdgcn_mfma_f32_16x16x32_bf16(ap0, vf0[nt], acc_o[nt], 0, 0, 0);
            acc_o[nt] = __builtin_amdgcn_mfma_f32_16x16x32_bf16(ap1, vf1[nt], acc_o[nt], 0, 0, 0);
        }
    }

    // ---- epilogue ----
    float invl[4];
#pragma unroll
    for (int r = 0; r < 4; ++r) invl[r] = 1.f / l_i[r];
#pragma unroll
    for (int nt = 0; nt < 4; ++nt)
#pragma unroll
        for (int r = 0; r < 4; ++r)
            out[qkbase + (size_t)(qt0 + g * 4 + r) * H_ + nt * 16 + col] =
                acc_o[nt][r] * invl[r];
}

// ---------------------------------------------------------------------------
extern "C" void kernel_launch(void* const* d_in, const int* in_sizes, int n_in,
                              void* d_out, int out_size, void* d_ws, size_t ws_size,
                              hipStream_t stream)
{
    // setup_inputs order: x, Wk, Wq, Wv
    const float* x  = (const float*)d_in[0];
    const float* Wk = (const float*)d_in[1];
    const float* Wq = (const float*)d_in[2];
    const float* Wv = (const float*)d_in[3];
    float* out = (float*)d_out;

    short* WT = (short*)d_ws;                       // [192][1024]
    short* qb = WT + (size_t)192 * C_;              // [B*T][64] bf16
    short* kb = qb + (size_t)B_ * T_ * H_;          // [B*T][64] bf16
    short* vT = kb + (size_t)B_ * T_ * H_;          // [B][64][T] bf16

    wtrans_kernel<<<dim3(192), 256, 0, stream>>>(Wq, Wk, Wv, WT);
    proj_kernel<<<dim3((B_ * T_) / 64), 256, 0, stream>>>(x, WT, qb, kb, vT);
    attn_kernel<<<dim3(T_ / 64, B_), 256, 0, stream>>>(qb, kb, vT, out);
}

// Round 3
// 76.484 us; speedup vs baseline: 4.6099x; 1.7286x over previous
//
#include <hip/hip_runtime.h>
#include <math.h>

#define B_ 8
#define T_ 2048
#define C_ 1024
#define H_ 64

typedef __attribute__((ext_vector_type(8))) short bf16x8;
typedef __attribute__((ext_vector_type(4))) float f32x4;

static __device__ __forceinline__ short f2bf(float f) {
    unsigned u = __float_as_uint(f);
    unsigned r = (u + 0x7FFFu + ((u >> 16) & 1u)) >> 16;   // RNE
    return (short)r;
}

// ---------------------------------------------------------------------------
// Kernel 0: WT[n][k] = W[k][n] as bf16. n: 0-63 = Wq cols, 64-127 = Wk, 128-191 = Wv.
// ---------------------------------------------------------------------------
__global__ __launch_bounds__(256) void wtrans_kernel(
    const float* __restrict__ Wq, const float* __restrict__ Wk,
    const float* __restrict__ Wv, short* __restrict__ WT)
{
    const int n  = blockIdx.x;          // 0..191
    const int k0 = threadIdx.x * 4;     // 0..1020
    const float* Wsel = (n < 64) ? Wq : (n < 128 ? Wk : Wv);
    const int h = n & 63;
    short4 pk;
    pk.x = f2bf(Wsel[(size_t)(k0 + 0) * H_ + h]);
    pk.y = f2bf(Wsel[(size_t)(k0 + 1) * H_ + h]);
    pk.z = f2bf(Wsel[(size_t)(k0 + 2) * H_ + h]);
    pk.w = f2bf(Wsel[(size_t)(k0 + 3) * H_ + h]);
    *reinterpret_cast<short4*>(&WT[(size_t)n * C_ + k0]) = pk;
}

// ---------------------------------------------------------------------------
// Kernel 1: MFMA projections. 32-row M-tiles -> 512 blocks (2/CU).
// 4 waves: wave (rs = w>>1) rows rs*16..+15, (ch = w&1) ntiles ch*6..ch*6+5.
// Outputs: q,k row-major bf16 [B*T][64]; v transposed bf16 [B][64][T].
// ---------------------------------------------------------------------------
__global__ __launch_bounds__(256) void proj_kernel(
    const float* __restrict__ x, const short* __restrict__ WT,
    short* __restrict__ qg, short* __restrict__ kg, short* __restrict__ vT)
{
    __shared__ short Xs[32][72];
    __shared__ short Ws[192][72];

    const int tid  = threadIdx.x;
    const int m0   = blockIdx.x * 32;
    const int w    = tid >> 6;
    const int rs   = w >> 1;
    const int ch   = w & 1;
    const int lane = tid & 63;
    const int col  = lane & 15;
    const int g    = lane >> 4;

    f32x4 acc[6];
#pragma unroll
    for (int nt = 0; nt < 6; ++nt) acc[nt] = (f32x4){0.f, 0.f, 0.f, 0.f};

    for (int kb = 0; kb < C_; kb += 64) {
        __syncthreads();
        // stage X tile 32x64 (f32 -> bf16): thread row tid>>3, 8 elems at (tid&7)*8
        {
            const int r  = tid >> 3;
            const int c8 = (tid & 7) * 8;
            const float4* src = reinterpret_cast<const float4*>(
                &x[(size_t)(m0 + r) * C_ + kb + c8]);
            float4 a0 = src[0], a1 = src[1];
            bf16x8 v0;
            v0[0] = f2bf(a0.x); v0[1] = f2bf(a0.y); v0[2] = f2bf(a0.z); v0[3] = f2bf(a0.w);
            v0[4] = f2bf(a1.x); v0[5] = f2bf(a1.y); v0[6] = f2bf(a1.z); v0[7] = f2bf(a1.w);
            *reinterpret_cast<bf16x8*>(&Xs[r][c8]) = v0;
        }
        // stage W^T tile: 192 rows x 64 k bf16
#pragma unroll
        for (int t = 0; t < 6; ++t) {
            int idx = tid + t * 256;
            int row = idx >> 3;
            int c8  = (idx & 7) * 8;
            bf16x8 wv = *reinterpret_cast<const bf16x8*>(&WT[(size_t)row * C_ + kb + c8]);
            *reinterpret_cast<bf16x8*>(&Ws[row][c8]) = wv;
        }
        __syncthreads();

        bf16x8 a0 = *reinterpret_cast<const bf16x8*>(&Xs[rs * 16 + col][g * 8]);
        bf16x8 a1 = *reinterpret_cast<const bf16x8*>(&Xs[rs * 16 + col][32 + g * 8]);
#pragma unroll
        for (int nt = 0; nt < 6; ++nt) {
            const int ng = ch * 6 + nt;
            bf16x8 b0 = *reinterpret_cast<const bf16x8*>(&Ws[ng * 16 + col][g * 8]);
            bf16x8 b1 = *reinterpret_cast<const bf16x8*>(&Ws[ng * 16 + col][32 + g * 8]);
            acc[nt] = __builtin_amdgcn_mfma_f32_16x16x32_bf16(a0, b0, acc[nt], 0, 0, 0);
            acc[nt] = __builtin_amdgcn_mfma_f32_16x16x32_bf16(a1, b1, acc[nt], 0, 0, 0);
        }
    }

    // epilogue: ntile global ng: 0-3 -> q, 4-7 -> k, 8-11 -> v(transposed)
    const int trow0 = m0 + rs * 16 + g * 4;
    const int bb    = trow0 >> 11;
    const int tloc  = trow0 & 2047;
#pragma unroll
    for (int nt = 0; nt < 6; ++nt) {
        const int ng = ch * 6 + nt;
        if (ng < 4) {
#pragma unroll
            for (int r = 0; r < 4; ++r)
                qg[(size_t)(trow0 + r) * H_ + ng * 16 + col] = f2bf(acc[nt][r]);
        } else if (ng < 8) {
#pragma unroll
            for (int r = 0; r < 4; ++r)
                kg[(size_t)(trow0 + r) * H_ + (ng - 4) * 16 + col] = f2bf(acc[nt][r]);
        } else {
            short4 pk;
            pk.x = f2bf(acc[nt][0]); pk.y = f2bf(acc[nt][1]);
            pk.z = f2bf(acc[nt][2]); pk.w = f2bf(acc[nt][3]);
            const int h = (ng - 8) * 16 + col;
            *reinterpret_cast<short4*>(&vT[((size_t)bb * H_ + h) * T_ + tloc]) = pk;
        }
    }
}

// ---------------------------------------------------------------------------
// Kernel 2: MFMA flash attention with intra-block split-KV.
// Grid (128, 8): block owns ONE 16-row q-tile; its 4 waves take key-blocks
// kb = w, w+4, ... with private (m,l,O); one barrier + LDS merge at the end.
// No __syncthreads in the main loop.
// ---------------------------------------------------------------------------
__global__ __launch_bounds__(256) void attn_kernel(
    const short* __restrict__ qg, const short* __restrict__ kg,
    const short* __restrict__ vT, float* __restrict__ out)
{
    __shared__ short Ps[4][16][72];    // wave-private P tile
    __shared__ float Ob[4][16][68];    // per-wave partial O
    __shared__ float Ml[4][16][2];     // per-wave (m, l)

    const int tid  = threadIdx.x;
    const int w    = tid >> 6;
    const int lane = tid & 63;
    const int col  = lane & 15;
    const int g    = lane >> 4;
    const int b    = blockIdx.y;
    const int j    = (int)(gridDim.x - 1) - (int)blockIdx.x;   // longest first
    const int qt0  = j * 16;
    const int n64  = (j >> 2) + 1;     // key-blocks of 64 covering 0..qt0+15

    const size_t qkbase = (size_t)b * T_ * H_;

    const bf16x8 qf0 = *reinterpret_cast<const bf16x8*>(
        &qg[qkbase + (size_t)(qt0 + col) * H_ + g * 8]);
    const bf16x8 qf1 = *reinterpret_cast<const bf16x8*>(
        &qg[qkbase + (size_t)(qt0 + col) * H_ + 32 + g * 8]);

    float m_i[4], l_i[4];
    f32x4 acc_o[4];
#pragma unroll
    for (int r = 0; r < 4; ++r) { m_i[r] = -INFINITY; l_i[r] = 0.f; }
#pragma unroll
    for (int nt = 0; nt < 4; ++nt) acc_o[nt] = (f32x4){0.f, 0.f, 0.f, 0.f};

    for (int kb = w; kb < n64; kb += 4) {
        // ---- K fragments (L2-resident) ----
        const short* kbp = &kg[qkbase + (size_t)kb * 64 * H_];
        bf16x8 kf0[4], kf1[4];
#pragma unroll
        for (int nt = 0; nt < 4; ++nt) {
            kf0[nt] = *reinterpret_cast<const bf16x8*>(&kbp[(nt * 16 + col) * H_ + g * 8]);
            kf1[nt] = *reinterpret_cast<const bf16x8*>(&kbp[(nt * 16 + col) * H_ + 32 + g * 8]);
        }
        f32x4 s[4];
#pragma unroll
        for (int nt = 0; nt < 4; ++nt) {
            s[nt] = (f32x4){0.f, 0.f, 0.f, 0.f};
            s[nt] = __builtin_amdgcn_mfma_f32_16x16x32_bf16(qf0, kf0[nt], s[nt], 0, 0, 0);
            s[nt] = __builtin_amdgcn_mfma_f32_16x16x32_bf16(qf1, kf1[nt], s[nt], 0, 0, 0);
        }

        // ---- V^T fragments issued early ----
        const short* vbp = &vT[(size_t)b * H_ * T_ + kb * 64];
        bf16x8 vf0[4], vf1[4];
#pragma unroll
        for (int nt = 0; nt < 4; ++nt) {
            vf0[nt] = *reinterpret_cast<const bf16x8*>(&vbp[(size_t)(nt * 16 + col) * T_ + g * 8]);
            vf1[nt] = *reinterpret_cast<const bf16x8*>(&vbp[(size_t)(nt * 16 + col) * T_ + 32 + g * 8]);
        }

        // ---- scale + causal mask (only diagonal key-block) ----
#pragma unroll
        for (int nt = 0; nt < 4; ++nt)
#pragma unroll
            for (int r = 0; r < 4; ++r) s[nt][r] *= 0.03125f;   // 1024^-0.5
        if (kb == n64 - 1) {
            const int roff = (j & 3) * 16 + g * 4;   // row offset within key-block
#pragma unroll
            for (int nt = 0; nt < 4; ++nt)
#pragma unroll
                for (int r = 0; r < 4; ++r)
                    if (nt * 16 + col > roff + r) s[nt][r] = -INFINITY;
        }

        // ---- online softmax (row g*4+r lives in lanes g*16..g*16+15) ----
        float mx[4];
#pragma unroll
        for (int r = 0; r < 4; ++r) {
            mx[r] = fmaxf(fmaxf(s[0][r], s[1][r]), fmaxf(s[2][r], s[3][r]));
            mx[r] = fmaxf(mx[r], __shfl_xor(mx[r], 1));
            mx[r] = fmaxf(mx[r], __shfl_xor(mx[r], 2));
            mx[r] = fmaxf(mx[r], __shfl_xor(mx[r], 4));
            mx[r] = fmaxf(mx[r], __shfl_xor(mx[r], 8));
        }
        float alpha[4];
#pragma unroll
        for (int r = 0; r < 4; ++r) {
            float mn = fmaxf(m_i[r], mx[r]);
            alpha[r] = __expf(m_i[r] - mn);
            m_i[r]   = mn;
        }
        float p[4][4];
#pragma unroll
        for (int nt = 0; nt < 4; ++nt)
#pragma unroll
            for (int r = 0; r < 4; ++r) p[nt][r] = __expf(s[nt][r] - m_i[r]);
        float lsum[4];
#pragma unroll
        for (int r = 0; r < 4; ++r) {
            lsum[r] = (p[0][r] + p[1][r]) + (p[2][r] + p[3][r]);
            lsum[r] += __shfl_xor(lsum[r], 1);
            lsum[r] += __shfl_xor(lsum[r], 2);
            lsum[r] += __shfl_xor(lsum[r], 4);
            lsum[r] += __shfl_xor(lsum[r], 8);
            l_i[r] = l_i[r] * alpha[r] + lsum[r];
        }
#pragma unroll
        for (int nt = 0; nt < 4; ++nt)
#pragma unroll
            for (int r = 0; r < 4; ++r) acc_o[nt][r] *= alpha[r];

        // ---- P -> LDS (bf16), re-read as A fragments (wave-private) ----
#pragma unroll
        for (int nt = 0; nt < 4; ++nt)
#pragma unroll
            for (int r = 0; r < 4; ++r)
                Ps[w][g * 4 + r][nt * 16 + col] = f2bf(p[nt][r]);

        bf16x8 ap0 = *reinterpret_cast<const bf16x8*>(&Ps[w][col][g * 8]);
        bf16x8 ap1 = *reinterpret_cast<const bf16x8*>(&Ps[w][col][32 + g * 8]);

#pragma unroll
        for (int nt = 0; nt < 4; ++nt) {
            acc_o[nt] = __builtin_amdgcn_mfma_f32_16x16x32_bf16(ap0, vf0[nt], acc_o[nt], 0, 0, 0);
            acc_o[nt] = __builtin_amdgcn_mfma_f32_16x16x32_bf16(ap1, vf1[nt], acc_o[nt], 0, 0, 0);
        }
    }

    // ---- merge the 4 waves' partials ----
#pragma unroll
    for (int nt = 0; nt < 4; ++nt)
#pragma unroll
        for (int r = 0; r < 4; ++r)
            Ob[w][g * 4 + r][nt * 16 + col] = acc_o[nt][r];
    if (col == 0) {
#pragma unroll
        for (int r = 0; r < 4; ++r) {
            Ml[w][g * 4 + r][0] = m_i[r];
            Ml[w][g * 4 + r][1] = l_i[r];
        }
    }
    __syncthreads();

    // wave w writes output quadrant nt = w
#pragma unroll
    for (int r = 0; r < 4; ++r) {
        const int row = g * 4 + r;
        float m0w = Ml[0][row][0], m1w = Ml[1][row][0];
        float m2w = Ml[2][row][0], m3w = Ml[3][row][0];
        float ms = fmaxf(fmaxf(m0w, m1w), fmaxf(m2w, m3w));
        float a0 = __expf(m0w - ms), a1 = __expf(m1w - ms);
        float a2 = __expf(m2w - ms), a3 = __expf(m3w - ms);
        float ls = Ml[0][row][1] * a0 + Ml[1][row][1] * a1
                 + Ml[2][row][1] * a2 + Ml[3][row][1] * a3;
        float o = Ob[0][row][w * 16 + col] * a0 + Ob[1][row][w * 16 + col] * a1
                + Ob[2][row][w * 16 + col] * a2 + Ob[3][row][w * 16 + col] * a3;
        out[qkbase + (size_t)(qt0 + row) * H_ + w * 16 + col] = o / ls;
    }
}

// ---------------------------------------------------------------------------
extern "C" void kernel_launch(void* const* d_in, const int* in_sizes, int n_in,
                              void* d_out, int out_size, void* d_ws, size_t ws_size,
                              hipStream_t stream)
{
    // setup_inputs order: x, Wk, Wq, Wv
    const float* x  = (const float*)d_in[0];
    const float* Wk = (const float*)d_in[1];
    const float* Wq = (const float*)d_in[2];
    const float* Wv = (const float*)d_in[3];
    float* out = (float*)d_out;

    short* WT = (short*)d_ws;                       // [192][1024]
    short* qb = WT + (size_t)192 * C_;              // [B*T][64] bf16
    short* kb = qb + (size_t)B_ * T_ * H_;          // [B*T][64] bf16
    short* vT = kb + (size_t)B_ * T_ * H_;          // [B][64][T] bf16

    wtrans_kernel<<<dim3(192), 256, 0, stream>>>(Wq, Wk, Wv, WT);
    proj_kernel<<<dim3((B_ * T_) / 32), 256, 0, stream>>>(x, WT, qb, kb, vT);
    attn_kernel<<<dim3(T_ / 16, B_), 256, 0, stream>>>(qb, kb, vT, out);
}

// Round 5
// 74.150 us; speedup vs baseline: 4.7550x; 1.0315x over previous
//
#include <hip/hip_runtime.h>
#include <math.h>

#define B_ 8
#define T_ 2048
#define C_ 1024
#define H_ 64

typedef __attribute__((ext_vector_type(8))) short bf16x8;
typedef __attribute__((ext_vector_type(4))) float f32x4;
typedef __attribute__((ext_vector_type(4))) unsigned u32x4;
typedef __attribute__((ext_vector_type(2))) unsigned u32x2;

static __device__ __forceinline__ short f2bf(float f) {
    unsigned u = __float_as_uint(f);
    unsigned r = (u + 0x7FFFu + ((u >> 16) & 1u)) >> 16;   // RNE
    return (short)r;
}

// hardware packed f32->bf16 (RNE)
static __device__ __forceinline__ unsigned cvt_pk_bf16(float lo, float hi) {
    unsigned r;
    asm("v_cvt_pk_bf16_f32 %0, %1, %2" : "=v"(r) : "v"(lo), "v"(hi));
    return r;
}

// permlane swaps via builtins: return BOTH results; safe under register
// coalescing (the round-4 asm version broke when a==b aliased one VGPR).
static __device__ __forceinline__ u32x2 p32(unsigned a, unsigned b) {
    return __builtin_amdgcn_permlane32_swap(a, b, false, false);
}
static __device__ __forceinline__ u32x2 p16(unsigned a, unsigned b) {
    return __builtin_amdgcn_permlane16_swap(a, b, false, false);
}
static __device__ __forceinline__ float xmax32(float x) {
    u32x2 r = p32(__float_as_uint(x), __float_as_uint(x));
    return fmaxf(__uint_as_float(r[0]), __uint_as_float(r[1]));
}
static __device__ __forceinline__ float xmax16(float x) {
    u32x2 r = p16(__float_as_uint(x), __float_as_uint(x));
    return fmaxf(__uint_as_float(r[0]), __uint_as_float(r[1]));
}
static __device__ __forceinline__ float xsum32(float x) {
    u32x2 r = p32(__float_as_uint(x), __float_as_uint(x));
    return __uint_as_float(r[0]) + __uint_as_float(r[1]);
}
static __device__ __forceinline__ float xsum16(float x) {
    u32x2 r = p16(__float_as_uint(x), __float_as_uint(x));
    return __uint_as_float(r[0]) + __uint_as_float(r[1]);
}

// ---------------------------------------------------------------------------
// Kernel 0: WT[n][k] = W[k][n] as bf16. n: 0-63 = Wq cols, 64-127 = Wk, 128-191 = Wv.
// ---------------------------------------------------------------------------
__global__ __launch_bounds__(256) void wtrans_kernel(
    const float* __restrict__ Wq, const float* __restrict__ Wk,
    const float* __restrict__ Wv, short* __restrict__ WT)
{
    const int n  = blockIdx.x;          // 0..191
    const int k0 = threadIdx.x * 4;     // 0..1020
    const float* Wsel = (n < 64) ? Wq : (n < 128 ? Wk : Wv);
    const int h = n & 63;
    short4 pk;
    pk.x = f2bf(Wsel[(size_t)(k0 + 0) * H_ + h]);
    pk.y = f2bf(Wsel[(size_t)(k0 + 1) * H_ + h]);
    pk.z = f2bf(Wsel[(size_t)(k0 + 2) * H_ + h]);
    pk.w = f2bf(Wsel[(size_t)(k0 + 3) * H_ + h]);
    *reinterpret_cast<short4*>(&WT[(size_t)n * C_ + k0]) = pk;
}

// ---------------------------------------------------------------------------
// Kernel 1: MFMA projections. 32-row M-tiles -> 512 blocks.
// Outputs: q,k row-major bf16 [B*T][64]; v transposed bf16 [B][64][T].
// ---------------------------------------------------------------------------
__global__ __launch_bounds__(256) void proj_kernel(
    const float* __restrict__ x, const short* __restrict__ WT,
    short* __restrict__ qg, short* __restrict__ kg, short* __restrict__ vT)
{
    __shared__ short Xs[32][72];
    __shared__ short Ws[192][72];

    const int tid  = threadIdx.x;
    const int m0   = blockIdx.x * 32;
    const int w    = tid >> 6;
    const int rs   = w >> 1;
    const int ch   = w & 1;
    const int lane = tid & 63;
    const int col  = lane & 15;
    const int g    = lane >> 4;

    f32x4 acc[6];
#pragma unroll
    for (int nt = 0; nt < 6; ++nt) acc[nt] = (f32x4){0.f, 0.f, 0.f, 0.f};

    for (int kb = 0; kb < C_; kb += 64) {
        __syncthreads();
        {
            const int r  = tid >> 3;
            const int c8 = (tid & 7) * 8;
            const float4* src = reinterpret_cast<const float4*>(
                &x[(size_t)(m0 + r) * C_ + kb + c8]);
            float4 a0 = src[0], a1 = src[1];
            bf16x8 v0;
            v0[0] = f2bf(a0.x); v0[1] = f2bf(a0.y); v0[2] = f2bf(a0.z); v0[3] = f2bf(a0.w);
            v0[4] = f2bf(a1.x); v0[5] = f2bf(a1.y); v0[6] = f2bf(a1.z); v0[7] = f2bf(a1.w);
            *reinterpret_cast<bf16x8*>(&Xs[r][c8]) = v0;
        }
#pragma unroll
        for (int t = 0; t < 6; ++t) {
            int idx = tid + t * 256;
            int row = idx >> 3;
            int c8  = (idx & 7) * 8;
            bf16x8 wv = *reinterpret_cast<const bf16x8*>(&WT[(size_t)row * C_ + kb + c8]);
            *reinterpret_cast<bf16x8*>(&Ws[row][c8]) = wv;
        }
        __syncthreads();

        bf16x8 a0 = *reinterpret_cast<const bf16x8*>(&Xs[rs * 16 + col][g * 8]);
        bf16x8 a1 = *reinterpret_cast<const bf16x8*>(&Xs[rs * 16 + col][32 + g * 8]);
#pragma unroll
        for (int nt = 0; nt < 6; ++nt) {
            const int ng = ch * 6 + nt;
            bf16x8 b0 = *reinterpret_cast<const bf16x8*>(&Ws[ng * 16 + col][g * 8]);
            bf16x8 b1 = *reinterpret_cast<const bf16x8*>(&Ws[ng * 16 + col][32 + g * 8]);
            acc[nt] = __builtin_amdgcn_mfma_f32_16x16x32_bf16(a0, b0, acc[nt], 0, 0, 0);
            acc[nt] = __builtin_amdgcn_mfma_f32_16x16x32_bf16(a1, b1, acc[nt], 0, 0, 0);
        }
    }

    const int trow0 = m0 + rs * 16 + g * 4;
    const int bb    = trow0 >> 11;
    const int tloc  = trow0 & 2047;
#pragma unroll
    for (int nt = 0; nt < 6; ++nt) {
        const int ng = ch * 6 + nt;
        if (ng < 4) {
#pragma unroll
            for (int r = 0; r < 4; ++r)
                qg[(size_t)(trow0 + r) * H_ + ng * 16 + col] = f2bf(acc[nt][r]);
        } else if (ng < 8) {
#pragma unroll
            for (int r = 0; r < 4; ++r)
                kg[(size_t)(trow0 + r) * H_ + (ng - 4) * 16 + col] = f2bf(acc[nt][r]);
        } else {
            short4 pk;
            pk.x = f2bf(acc[nt][0]); pk.y = f2bf(acc[nt][1]);
            pk.z = f2bf(acc[nt][2]); pk.w = f2bf(acc[nt][3]);
            const int h = (ng - 8) * 16 + col;
            *reinterpret_cast<short4*>(&vT[((size_t)bb * H_ + h) * T_ + tloc]) = pk;
        }
    }
}

// ---------------------------------------------------------------------------
// Kernel 2: MFMA flash attention, split-KV, fully in-register softmax.
// S^T = mfma(K, Q)  -> lane col = q, each lane owns its q-row's 16 P values.
// O^T = mfma(V^T, P^T) -> lane col = q, (m,l,alpha) rescale all lane-local.
// P f32->bf16 via v_cvt_pk_bf16_f32; fragment redistribution via
// permlane32_swap + permlane16_swap builtins. No LDS ops in the main loop.
// ---------------------------------------------------------------------------
__global__ __launch_bounds__(256) void attn_kernel(
    const short* __restrict__ qg, const short* __restrict__ kg,
    const short* __restrict__ vT, float* __restrict__ out)
{
    __shared__ float Ob[4][16][68];    // per-wave partial O^T, padded
    __shared__ float Ml[4][16][2];     // per-wave (m, l)

    const int tid  = threadIdx.x;
    const int w    = tid >> 6;
    const int lane = tid & 63;
    const int col  = lane & 15;        // q within tile
    const int g    = lane >> 4;
    const int b    = blockIdx.y;
    const int j    = (int)(gridDim.x - 1) - (int)blockIdx.x;   // longest first
    const int qt0  = j * 16;
    const int n64  = (j >> 2) + 1;     // key-blocks of 64 covering 0..qt0+15

    const size_t qkbase = (size_t)b * T_ * H_;

    // Q as B-fragment: col = q, k-dim = h contiguous
    const bf16x8 qf0 = *reinterpret_cast<const bf16x8*>(
        &qg[qkbase + (size_t)(qt0 + col) * H_ + g * 8]);
    const bf16x8 qf1 = *reinterpret_cast<const bf16x8*>(
        &qg[qkbase + (size_t)(qt0 + col) * H_ + 32 + g * 8]);

    float m_i = -INFINITY, l_i = 0.f;
    f32x4 acc[4];
#pragma unroll
    for (int nt = 0; nt < 4; ++nt) acc[nt] = (f32x4){0.f, 0.f, 0.f, 0.f};

    for (int kb = w; kb < n64; kb += 4) {
        const short* kbp = &kg[qkbase + (size_t)kb * 64 * H_];
        const short* vbp = &vT[(size_t)b * H_ * T_ + kb * 64];

        // ---- S^T = K Q^T : s[nt][r] = S[k = nt*16+g*4+r][q = col] ----
        f32x4 s[4];
#pragma unroll
        for (int nt = 0; nt < 4; ++nt) {
            bf16x8 kf0 = *reinterpret_cast<const bf16x8*>(&kbp[(nt * 16 + col) * H_ + g * 8]);
            bf16x8 kf1 = *reinterpret_cast<const bf16x8*>(&kbp[(nt * 16 + col) * H_ + 32 + g * 8]);
            s[nt] = (f32x4){0.f, 0.f, 0.f, 0.f};
            s[nt] = __builtin_amdgcn_mfma_f32_16x16x32_bf16(kf0, qf0, s[nt], 0, 0, 0);
            s[nt] = __builtin_amdgcn_mfma_f32_16x16x32_bf16(kf1, qf1, s[nt], 0, 0, 0);
        }

        // ---- V^T fragments issued early (A-operand of O^T mfma) ----
        bf16x8 vf0[4], vf1[4];
#pragma unroll
        for (int nt = 0; nt < 4; ++nt) {
            vf0[nt] = *reinterpret_cast<const bf16x8*>(&vbp[(size_t)(nt * 16 + col) * T_ + g * 8]);
            vf1[nt] = *reinterpret_cast<const bf16x8*>(&vbp[(size_t)(nt * 16 + col) * T_ + 32 + g * 8]);
        }

        // ---- scale + causal mask (diagonal key-block only) ----
#pragma unroll
        for (int nt = 0; nt < 4; ++nt)
#pragma unroll
            for (int r = 0; r < 4; ++r) s[nt][r] *= 0.03125f;   // 1024^-0.5
        if (kb == n64 - 1) {
            const int kbase = kb * 64 + g * 4;
#pragma unroll
            for (int nt = 0; nt < 4; ++nt)
#pragma unroll
                for (int r = 0; r < 4; ++r)
                    if (kbase + nt * 16 + r > qt0 + col) s[nt][r] = -INFINITY;
        }

        // ---- lane-local softmax: 16 values local, cross-lane = 2 permlanes ----
        float mx = s[0][0];
#pragma unroll
        for (int nt = 0; nt < 4; ++nt)
#pragma unroll
            for (int r = 0; r < 4; ++r) mx = fmaxf(mx, s[nt][r]);
        mx = xmax32(mx);
        mx = xmax16(mx);

        const float mn    = fmaxf(m_i, mx);
        const float alpha = __expf(m_i - mn);
        m_i = mn;

        float p[4][4];
        float ls = 0.f;
#pragma unroll
        for (int nt = 0; nt < 4; ++nt)
#pragma unroll
            for (int r = 0; r < 4; ++r) {
                p[nt][r] = __expf(s[nt][r] - mn);
                ls += p[nt][r];
            }
        ls = xsum32(ls);
        ls = xsum16(ls);
        l_i = l_i * alpha + ls;

#pragma unroll
        for (int nt = 0; nt < 4; ++nt)
#pragma unroll
            for (int r = 0; r < 4; ++r) acc[nt][r] *= alpha;

        // ---- pack P into B-fragments in-register ----
        // word Wd[nt][rp] = bf16x2 of keys {nt*16 + g*4 + 2rp, +1} at q=col.
        unsigned Wd[4][2];
#pragma unroll
        for (int nt = 0; nt < 4; ++nt) {
            Wd[nt][0] = cvt_pk_bf16(p[nt][0], p[nt][1]);
            Wd[nt][1] = cvt_pk_bf16(p[nt][2], p[nt][3]);
        }
        // frag0 (keys 0..31) from Wd[0],Wd[1]; frag1 (keys 32..63) from Wd[2],Wd[3].
        // After p32 then p16 of (X=Wd[lo][rp], Y=Wd[hi][rp]):
        //   res0 = [X_0, X_2, Y_0, Y_2]  (per 16-lane group)
        //   res1 = [X_1, X_3, Y_1, Y_3]
        // giving lane-group g the keys {g*8..g*8+7} split across word slots 0&2.
        u32x2 t0, t1;
        t0 = p32(Wd[0][0], Wd[1][0]); t0 = p16(t0[0], t0[1]);
        t1 = p32(Wd[0][1], Wd[1][1]); t1 = p16(t1[0], t1[1]);
        u32x4 pw0 = (u32x4){t0[0], t1[0], t0[1], t1[1]};
        t0 = p32(Wd[2][0], Wd[3][0]); t0 = p16(t0[0], t0[1]);
        t1 = p32(Wd[2][1], Wd[3][1]); t1 = p16(t1[0], t1[1]);
        u32x4 pw1 = (u32x4){t0[0], t1[0], t0[1], t1[1]};
        bf16x8 pa0 = *reinterpret_cast<bf16x8*>(&pw0);
        bf16x8 pa1 = *reinterpret_cast<bf16x8*>(&pw1);

        // ---- O^T += V^T P^T ----
#pragma unroll
        for (int nt = 0; nt < 4; ++nt) {
            acc[nt] = __builtin_amdgcn_mfma_f32_16x16x32_bf16(vf0[nt], pa0, acc[nt], 0, 0, 0);
            acc[nt] = __builtin_amdgcn_mfma_f32_16x16x32_bf16(vf1[nt], pa1, acc[nt], 0, 0, 0);
        }
    }

    // ---- merge the 4 waves' partials (single barrier) ----
#pragma unroll
    for (int nt = 0; nt < 4; ++nt)
        *reinterpret_cast<f32x4*>(&Ob[w][col][nt * 16 + g * 4]) = acc[nt];
    if (g == 0) {
        Ml[w][col][0] = m_i;
        Ml[w][col][1] = l_i;
    }
    __syncthreads();

    // wave w writes h-quadrant w; lane (col,g): q=col, h=w*16+g*4..+3
    float ms = -INFINITY;
#pragma unroll
    for (int w2 = 0; w2 < 4; ++w2) ms = fmaxf(ms, Ml[w2][col][0]);
    float lsum = 0.f;
    float o0 = 0.f, o1 = 0.f, o2 = 0.f, o3 = 0.f;
#pragma unroll
    for (int w2 = 0; w2 < 4; ++w2) {
        const float a = __expf(Ml[w2][col][0] - ms);
        lsum += Ml[w2][col][1] * a;
        const float* ob = &Ob[w2][col][w * 16 + g * 4];
        o0 += a * ob[0]; o1 += a * ob[1]; o2 += a * ob[2]; o3 += a * ob[3];
    }
    const float inv = 1.f / lsum;
    f32x4 res = (f32x4){o0 * inv, o1 * inv, o2 * inv, o3 * inv};
    *reinterpret_cast<f32x4*>(&out[qkbase + (size_t)(qt0 + col) * H_ + w * 16 + g * 4]) = res;
}

// ---------------------------------------------------------------------------
extern "C" void kernel_launch(void* const* d_in, const int* in_sizes, int n_in,
                              void* d_out, int out_size, void* d_ws, size_t ws_size,
                              hipStream_t stream)
{
    // setup_inputs order: x, Wk, Wq, Wv
    const float* x  = (const float*)d_in[0];
    const float* Wk = (const float*)d_in[1];
    const float* Wq = (const float*)d_in[2];
    const float* Wv = (const float*)d_in[3];
    float* out = (float*)d_out;

    short* WT = (short*)d_ws;                       // [192][1024]
    short* qb = WT + (size_t)192 * C_;              // [B*T][64] bf16
    short* kb = qb + (size_t)B_ * T_ * H_;          // [B*T][64] bf16
    short* vT = kb + (size_t)B_ * T_ * H_;          // [B][64][T] bf16

    wtrans_kernel<<<dim3(192), 256, 0, stream>>>(Wq, Wk, Wv, WT);
    proj_kernel<<<dim3((B_ * T_) / 32), 256, 0, stream>>>(x, WT, qb, kb, vT);
    attn_kernel<<<dim3(T_ / 16, B_), 256, 0, stream>>>(qb, kb, vT, out);
}

// Round 6
// 62.916 us; speedup vs baseline: 5.6040x; 1.1786x over previous
//
#include <hip/hip_runtime.h>
#include <math.h>

#define B_ 8
#define T_ 2048
#define C_ 1024
#define H_ 64

typedef __attribute__((ext_vector_type(8))) short bf16x8;
typedef __attribute__((ext_vector_type(4))) float f32x4;
typedef __attribute__((ext_vector_type(16))) float f32x16;
typedef __attribute__((ext_vector_type(4))) unsigned u32x4;
typedef __attribute__((ext_vector_type(2))) unsigned u32x2;

static __device__ __forceinline__ short f2bf(float f) {
    unsigned u = __float_as_uint(f);
    unsigned r = (u + 0x7FFFu + ((u >> 16) & 1u)) >> 16;   // RNE
    return (short)r;
}

// hardware packed f32->bf16 (RNE)
static __device__ __forceinline__ unsigned cvt_pk_bf16(float lo, float hi) {
    unsigned r;
    asm("v_cvt_pk_bf16_f32 %0, %1, %2" : "=v"(r) : "v"(lo), "v"(hi));
    return r;
}

// permlane swaps via builtins (return both results; alias-safe)
static __device__ __forceinline__ u32x2 p32(unsigned a, unsigned b) {
    return __builtin_amdgcn_permlane32_swap(a, b, false, false);
}
static __device__ __forceinline__ float xmax32(float x) {
    u32x2 r = p32(__float_as_uint(x), __float_as_uint(x));
    return fmaxf(__uint_as_float(r[0]), __uint_as_float(r[1]));
}
static __device__ __forceinline__ float xsum32(float x) {
    u32x2 r = p32(__float_as_uint(x), __float_as_uint(x));
    return __uint_as_float(r[0]) + __uint_as_float(r[1]);
}

// ---------------------------------------------------------------------------
// Kernel 0: WT[n][k] = W[k][n] as bf16. n: 0-63 = Wq cols, 64-127 = Wk, 128-191 = Wv.
// ---------------------------------------------------------------------------
__global__ __launch_bounds__(256) void wtrans_kernel(
    const float* __restrict__ Wq, const float* __restrict__ Wk,
    const float* __restrict__ Wv, short* __restrict__ WT)
{
    const int n  = blockIdx.x;          // 0..191
    const int k0 = threadIdx.x * 4;     // 0..1020
    const float* Wsel = (n < 64) ? Wq : (n < 128 ? Wk : Wv);
    const int h = n & 63;
    short4 pk;
    pk.x = f2bf(Wsel[(size_t)(k0 + 0) * H_ + h]);
    pk.y = f2bf(Wsel[(size_t)(k0 + 1) * H_ + h]);
    pk.z = f2bf(Wsel[(size_t)(k0 + 2) * H_ + h]);
    pk.w = f2bf(Wsel[(size_t)(k0 + 3) * H_ + h]);
    *reinterpret_cast<short4*>(&WT[(size_t)n * C_ + k0]) = pk;
}

// ---------------------------------------------------------------------------
// Kernel 1: MFMA projections. 32-row M-tiles -> 512 blocks.
// Outputs: q,k row-major bf16 [B*T][64]; v transposed bf16 [B][64][T].
// ---------------------------------------------------------------------------
__global__ __launch_bounds__(256) void proj_kernel(
    const float* __restrict__ x, const short* __restrict__ WT,
    short* __restrict__ qg, short* __restrict__ kg, short* __restrict__ vT)
{
    __shared__ short Xs[32][72];
    __shared__ short Ws[192][72];

    const int tid  = threadIdx.x;
    const int m0   = blockIdx.x * 32;
    const int w    = tid >> 6;
    const int rs   = w >> 1;
    const int ch   = w & 1;
    const int lane = tid & 63;
    const int col  = lane & 15;
    const int g    = lane >> 4;

    f32x4 acc[6];
#pragma unroll
    for (int nt = 0; nt < 6; ++nt) acc[nt] = (f32x4){0.f, 0.f, 0.f, 0.f};

    for (int kb = 0; kb < C_; kb += 64) {
        __syncthreads();
        {
            const int r  = tid >> 3;
            const int c8 = (tid & 7) * 8;
            const float4* src = reinterpret_cast<const float4*>(
                &x[(size_t)(m0 + r) * C_ + kb + c8]);
            float4 a0 = src[0], a1 = src[1];
            bf16x8 v0;
            v0[0] = f2bf(a0.x); v0[1] = f2bf(a0.y); v0[2] = f2bf(a0.z); v0[3] = f2bf(a0.w);
            v0[4] = f2bf(a1.x); v0[5] = f2bf(a1.y); v0[6] = f2bf(a1.z); v0[7] = f2bf(a1.w);
            *reinterpret_cast<bf16x8*>(&Xs[r][c8]) = v0;
        }
#pragma unroll
        for (int t = 0; t < 6; ++t) {
            int idx = tid + t * 256;
            int row = idx >> 3;
            int c8  = (idx & 7) * 8;
            bf16x8 wv = *reinterpret_cast<const bf16x8*>(&WT[(size_t)row * C_ + kb + c8]);
            *reinterpret_cast<bf16x8*>(&Ws[row][c8]) = wv;
        }
        __syncthreads();

        bf16x8 a0 = *reinterpret_cast<const bf16x8*>(&Xs[rs * 16 + col][g * 8]);
        bf16x8 a1 = *reinterpret_cast<const bf16x8*>(&Xs[rs * 16 + col][32 + g * 8]);
#pragma unroll
        for (int nt = 0; nt < 6; ++nt) {
            const int ng = ch * 6 + nt;
            bf16x8 b0 = *reinterpret_cast<const bf16x8*>(&Ws[ng * 16 + col][g * 8]);
            bf16x8 b1 = *reinterpret_cast<const bf16x8*>(&Ws[ng * 16 + col][32 + g * 8]);
            acc[nt] = __builtin_amdgcn_mfma_f32_16x16x32_bf16(a0, b0, acc[nt], 0, 0, 0);
            acc[nt] = __builtin_amdgcn_mfma_f32_16x16x32_bf16(a1, b1, acc[nt], 0, 0, 0);
        }
    }

    const int trow0 = m0 + rs * 16 + g * 4;
    const int bb    = trow0 >> 11;
    const int tloc  = trow0 & 2047;
#pragma unroll
    for (int nt = 0; nt < 6; ++nt) {
        const int ng = ch * 6 + nt;
        if (ng < 4) {
#pragma unroll
            for (int r = 0; r < 4; ++r)
                qg[(size_t)(trow0 + r) * H_ + ng * 16 + col] = f2bf(acc[nt][r]);
        } else if (ng < 8) {
#pragma unroll
            for (int r = 0; r < 4; ++r)
                kg[(size_t)(trow0 + r) * H_ + (ng - 4) * 16 + col] = f2bf(acc[nt][r]);
        } else {
            short4 pk;
            pk.x = f2bf(acc[nt][0]); pk.y = f2bf(acc[nt][1]);
            pk.z = f2bf(acc[nt][2]); pk.w = f2bf(acc[nt][3]);
            const int h = (ng - 8) * 16 + col;
            *reinterpret_cast<short4*>(&vT[((size_t)bb * H_ + h) * T_ + tloc]) = pk;
        }
    }
}

// ---------------------------------------------------------------------------
// Kernel 2: MFMA flash attention, 32x32x16 wave-tiles, split-KV, in-register
// softmax. Block = 32 q-rows, 4 waves strided over 64-key blocks.
// S^T = mfma32(K, Q): lane ln=l&31 owns q-row qt0+ln; lane pair (l, l^32)
// holds complementary key halves -> row reduce = ONE permlane32_swap.
// O^T = mfma32(V^T, P^T): (m,l,alpha) fully lane-local.
// P packed in-register: cvt_pk + 2 permlane32_swap per 16-key B-fragment.
// No LDS in the main loop; one barrier + 4-way merge at the end.
// ---------------------------------------------------------------------------
__global__ __launch_bounds__(256) void attn_kernel(
    const short* __restrict__ qg, const short* __restrict__ kg,
    const short* __restrict__ vT, float* __restrict__ out)
{
    __shared__ float Ob[4][32][68];    // per-wave partial O^T [w][q][h]
    __shared__ float Ml[4][32][2];     // per-wave (m, l)

    const int tid  = threadIdx.x;
    const int w    = tid >> 6;
    const int lane = tid & 63;
    const int ln   = lane & 31;        // q within tile / A-row
    const int hi   = lane >> 5;        // k-half selector
    const int b    = blockIdx.y;
    const int j    = (int)(gridDim.x - 1) - (int)blockIdx.x;   // longest first
    const int qt0  = j * 32;
    const int n64  = (j >> 1) + 1;     // 64-key blocks covering 0..qt0+31

    const size_t qkbase = (size_t)b * T_ * H_;

    // Q as B-fragments for the 4 h-tiles: k = 16*ht + 8*hi + e
    bf16x8 qf[4];
#pragma unroll
    for (int ht = 0; ht < 4; ++ht)
        qf[ht] = *reinterpret_cast<const bf16x8*>(
            &qg[qkbase + (size_t)(qt0 + ln) * H_ + ht * 16 + hi * 8]);

    float m_i = -INFINITY, l_i = 0.f;
    f32x16 acc0, acc1;                 // O^T h 0..31 / 32..63
#pragma unroll
    for (int r = 0; r < 16; ++r) { acc0[r] = 0.f; acc1[r] = 0.f; }

    for (int kb = w; kb < n64; kb += 4) {
        const short* kbp = &kg[qkbase + (size_t)kb * 64 * H_];
        const short* vbp = &vT[(size_t)b * H_ * T_ + (size_t)kb * 64];

        // ---- S^T tiles (keys kb*64 + t*32 + ...) ----
        f32x16 s0, s1;
#pragma unroll
        for (int r = 0; r < 16; ++r) { s0[r] = 0.f; s1[r] = 0.f; }
#pragma unroll
        for (int ht = 0; ht < 4; ++ht) {
            bf16x8 ka0 = *reinterpret_cast<const bf16x8*>(
                &kbp[(size_t)ln * H_ + ht * 16 + hi * 8]);
            bf16x8 ka1 = *reinterpret_cast<const bf16x8*>(
                &kbp[(size_t)(32 + ln) * H_ + ht * 16 + hi * 8]);
            s0 = __builtin_amdgcn_mfma_f32_32x32x16_bf16(ka0, qf[ht], s0, 0, 0, 0);
            s1 = __builtin_amdgcn_mfma_f32_32x32x16_bf16(ka1, qf[ht], s1, 0, 0, 0);
        }

        // ---- V^T A-fragments issued early: va[hs][kt], key = 16kt+8hi+e ----
        bf16x8 va[2][4];
#pragma unroll
        for (int hs = 0; hs < 2; ++hs)
#pragma unroll
            for (int kt = 0; kt < 4; ++kt)
                va[hs][kt] = *reinterpret_cast<const bf16x8*>(
                    &vbp[(size_t)(hs * 32 + ln) * T_ + kt * 16 + hi * 8]);

        // ---- scale + causal mask (diagonal block only) ----
#pragma unroll
        for (int r = 0; r < 16; ++r) { s0[r] *= 0.03125f; s1[r] *= 0.03125f; }
        if (kb == n64 - 1) {
            const int qglob = qt0 + ln;
            const int kb0   = kb * 64 + hi * 4;
#pragma unroll
            for (int r = 0; r < 16; ++r) {
                const int key = kb0 + (r & 3) + 8 * (r >> 2);
                if (key > qglob)      s0[r] = -INFINITY;
                if (key + 32 > qglob) s1[r] = -INFINITY;
            }
        }

        // ---- lane-local softmax (32 local values + 1 permlane swap) ----
        float mx = s0[0];
#pragma unroll
        for (int r = 1; r < 16; ++r) mx = fmaxf(mx, s0[r]);
#pragma unroll
        for (int r = 0; r < 16; ++r) mx = fmaxf(mx, s1[r]);
        mx = xmax32(mx);

        const float mn    = fmaxf(m_i, mx);
        const float alpha = __expf(m_i - mn);
        m_i = mn;

        float p0[16], p1[16];
        float ls = 0.f;
#pragma unroll
        for (int r = 0; r < 16; ++r) {
            p0[r] = __expf(s0[r] - mn);
            p1[r] = __expf(s1[r] - mn);
            ls += p0[r] + p1[r];
        }
        ls = xsum32(ls);
        l_i = l_i * alpha + ls;

#pragma unroll
        for (int r = 0; r < 16; ++r) { acc0[r] *= alpha; acc1[r] *= alpha; }

        // ---- pack P^T into B-fragments (keys 16kt+8hi+e at q=ln) ----
        // tile0 (keys 0..31): regs r -> key (r&3)+8*(r>>2)+4*hi
        unsigned W0 = cvt_pk_bf16(p0[0],  p0[1]);
        unsigned W1 = cvt_pk_bf16(p0[2],  p0[3]);
        unsigned W2 = cvt_pk_bf16(p0[4],  p0[5]);
        unsigned W3 = cvt_pk_bf16(p0[6],  p0[7]);
        unsigned W4 = cvt_pk_bf16(p0[8],  p0[9]);
        unsigned W5 = cvt_pk_bf16(p0[10], p0[11]);
        unsigned W6 = cvt_pk_bf16(p0[12], p0[13]);
        unsigned W7 = cvt_pk_bf16(p0[14], p0[15]);
        u32x2 ra = p32(W0, W2), rb = p32(W1, W3);
        u32x4 bw0 = (u32x4){ra[0], rb[0], ra[1], rb[1]};   // keys 0..15
        ra = p32(W4, W6); rb = p32(W5, W7);
        u32x4 bw1 = (u32x4){ra[0], rb[0], ra[1], rb[1]};   // keys 16..31
        W0 = cvt_pk_bf16(p1[0],  p1[1]);
        W1 = cvt_pk_bf16(p1[2],  p1[3]);
        W2 = cvt_pk_bf16(p1[4],  p1[5]);
        W3 = cvt_pk_bf16(p1[6],  p1[7]);
        W4 = cvt_pk_bf16(p1[8],  p1[9]);
        W5 = cvt_pk_bf16(p1[10], p1[11]);
        W6 = cvt_pk_bf16(p1[12], p1[13]);
        W7 = cvt_pk_bf16(p1[14], p1[15]);
        ra = p32(W0, W2); rb = p32(W1, W3);
        u32x4 bw2 = (u32x4){ra[0], rb[0], ra[1], rb[1]};   // keys 32..47
        ra = p32(W4, W6); rb = p32(W5, W7);
        u32x4 bw3 = (u32x4){ra[0], rb[0], ra[1], rb[1]};   // keys 48..63
        bf16x8 pb0 = *reinterpret_cast<bf16x8*>(&bw0);
        bf16x8 pb1 = *reinterpret_cast<bf16x8*>(&bw1);
        bf16x8 pb2 = *reinterpret_cast<bf16x8*>(&bw2);
        bf16x8 pb3 = *reinterpret_cast<bf16x8*>(&bw3);

        // ---- O^T += V^T P^T ----
        acc0 = __builtin_amdgcn_mfma_f32_32x32x16_bf16(va[0][0], pb0, acc0, 0, 0, 0);
        acc1 = __builtin_amdgcn_mfma_f32_32x32x16_bf16(va[1][0], pb0, acc1, 0, 0, 0);
        acc0 = __builtin_amdgcn_mfma_f32_32x32x16_bf16(va[0][1], pb1, acc0, 0, 0, 0);
        acc1 = __builtin_amdgcn_mfma_f32_32x32x16_bf16(va[1][1], pb1, acc1, 0, 0, 0);
        acc0 = __builtin_amdgcn_mfma_f32_32x32x16_bf16(va[0][2], pb2, acc0, 0, 0, 0);
        acc1 = __builtin_amdgcn_mfma_f32_32x32x16_bf16(va[1][2], pb2, acc1, 0, 0, 0);
        acc0 = __builtin_amdgcn_mfma_f32_32x32x16_bf16(va[0][3], pb3, acc0, 0, 0, 0);
        acc1 = __builtin_amdgcn_mfma_f32_32x32x16_bf16(va[1][3], pb3, acc1, 0, 0, 0);
    }

    // ---- store partials: acc reg r -> h = (r&3) + 8*(r>>2) + 4*hi ----
#pragma unroll
    for (int part = 0; part < 4; ++part) {
        f32x4 v0 = (f32x4){acc0[part*4+0], acc0[part*4+1], acc0[part*4+2], acc0[part*4+3]};
        f32x4 v1 = (f32x4){acc1[part*4+0], acc1[part*4+1], acc1[part*4+2], acc1[part*4+3]};
        *reinterpret_cast<f32x4*>(&Ob[w][ln][hi * 4 + part * 8])      = v0;
        *reinterpret_cast<f32x4*>(&Ob[w][ln][32 + hi * 4 + part * 8]) = v1;
    }
    if (hi == 0) {
        Ml[w][ln][0] = m_i;
        Ml[w][ln][1] = l_i;
    }
    __syncthreads();

    // ---- 4-way merge; wave w covers h = w*16 + hi*8 .. +7 for q = ln ----
    float ms = -INFINITY;
#pragma unroll
    for (int w2 = 0; w2 < 4; ++w2) ms = fmaxf(ms, Ml[w2][ln][0]);
    float lsum = 0.f;
    float o[8];
#pragma unroll
    for (int e = 0; e < 8; ++e) o[e] = 0.f;
    const int h0 = w * 16 + hi * 8;
#pragma unroll
    for (int w2 = 0; w2 < 4; ++w2) {
        const float a = __expf(Ml[w2][ln][0] - ms);
        lsum += Ml[w2][ln][1] * a;
        const float* ob = &Ob[w2][ln][h0];
#pragma unroll
        for (int e = 0; e < 8; ++e) o[e] += a * ob[e];
    }
    const float inv = 1.f / lsum;
    f32x4 r0 = (f32x4){o[0] * inv, o[1] * inv, o[2] * inv, o[3] * inv};
    f32x4 r1 = (f32x4){o[4] * inv, o[5] * inv, o[6] * inv, o[7] * inv};
    float* op = &out[qkbase + (size_t)(qt0 + ln) * H_ + h0];
    *reinterpret_cast<f32x4*>(op)     = r0;
    *reinterpret_cast<f32x4*>(op + 4) = r1;
}

// ---------------------------------------------------------------------------
extern "C" void kernel_launch(void* const* d_in, const int* in_sizes, int n_in,
                              void* d_out, int out_size, void* d_ws, size_t ws_size,
                              hipStream_t stream)
{
    // setup_inputs order: x, Wk, Wq, Wv
    const float* x  = (const float*)d_in[0];
    const float* Wk = (const float*)d_in[1];
    const float* Wq = (const float*)d_in[2];
    const float* Wv = (const float*)d_in[3];
    float* out = (float*)d_out;

    short* WT = (short*)d_ws;                       // [192][1024]
    short* qb = WT + (size_t)192 * C_;              // [B*T][64] bf16
    short* kb = qb + (size_t)B_ * T_ * H_;          // [B*T][64] bf16
    short* vT = kb + (size_t)B_ * T_ * H_;          // [B][64][T] bf16

    wtrans_kernel<<<dim3(192), 256, 0, stream>>>(Wq, Wk, Wv, WT);
    proj_kernel<<<dim3((B_ * T_) / 32), 256, 0, stream>>>(x, WT, qb, kb, vT);
    attn_kernel<<<dim3(T_ / 32, B_), 256, 0, stream>>>(qb, kb, vT, out);
}